// Round 1
// 56.103 us; speedup vs baseline: 1.0231x; 1.0231x over previous
//
#include <hip/hip_runtime.h>

// Chamfer distance, B=4, N=M=8192, fp32 [B][N][3], out[B] = d01+d10.
//
// VALU-issue-bound (no fp32 MFMA on CDNA4). This round: Q=8 -> Q=16
// register-resident queries per thread, halving LDS read traffic per pair
// (LDS pipe was ~86% of the VALU issue pole) and halving loop overhead.
// To fit VGPRs, |q|^2 is evicted from the hot kernel: we atomicMax an
// order-preserving key of max d' (d' = q.p - 0.5|p|^2, monotone in dist),
// and the finalize pass reconstructs dist = |q|^2 - 2*maxd' from the
// query cloud.

typedef float f32x2 __attribute__((ext_vector_type(2)));

constexpr int B      = 4;
constexpr int NPTS   = 8192;
constexpr int BLOCK  = 256;
constexpr int Q      = 16;              // queries per thread (reg-resident)
constexpr int QPB    = BLOCK * Q;       // 4096 queries per block
constexpr int QBLKS  = NPTS / QPB;      // 2
constexpr int CHUNKS = 32;
constexpr int TILE   = NPTS / CHUNKS;   // 256 db points per chunk
constexpr int PAIRS  = TILE / 2;        // 128 packed point-pairs (4 KB LDS)

__device__ inline f32x2 pk_fma(f32x2 a, f32x2 b, f32x2 c) {
    f32x2 d;
    asm("v_pk_fma_f32 %0, %1, %2, %3" : "=v"(d) : "v"(a), "v"(b), "v"(c));
    return d;
}

__device__ inline unsigned key_of(float f) {
    unsigned b = __float_as_uint(f);
    return b ^ (unsigned)(((int)b >> 31) | (int)0x80000000u);
}
__device__ inline float float_of(unsigned k) {
    unsigned b = (k & 0x80000000u) ? (k ^ 0x80000000u) : ~k;
    return __uint_as_float(b);
}

__global__ __launch_bounds__(BLOCK, 2) void chamfer_chunk(
    const float* __restrict__ tpl, const float* __restrict__ src,
    unsigned* __restrict__ keys)                 // [2*B][NPTS], key of max d'
{
    __shared__ float4 sA[PAIRS];   // (x0, x1, y0, y1)
    __shared__ float4 sB[PAIRS];   // (z0, z1, w0, w1), w = -0.5*|p|^2

    const int z   = blockIdx.z;                  // dir*B + b
    const int b   = z & (B - 1);
    const int dir = z >> 2;
    const float* q  = (dir == 0 ? tpl : src) + (size_t)b * NPTS * 3;
    const float* db = (dir == 0 ? src : tpl) + (size_t)b * NPTS * 3;

    // Stage this chunk as packed point-pairs (threads 0..PAIRS-1).
    if (threadIdx.x < PAIRS) {
        const int i = threadIdx.x;
        const float2* g2 = (const float2*)(db + (size_t)blockIdx.y * TILE * 3);
        float2 a = g2[3 * i], bb = g2[3 * i + 1], cc = g2[3 * i + 2];
        // p0 = (a.x, a.y, bb.x), p1 = (bb.y, cc.x, cc.y)
        float n0 = a.x * a.x + a.y * a.y + bb.x * bb.x;
        float n1 = bb.y * bb.y + cc.x * cc.x + cc.y * cc.y;
        sA[i] = make_float4(a.x, bb.y, a.y, cc.x);
        sB[i] = make_float4(bb.x, cc.y, -0.5f * n0, -0.5f * n1);
    }

    // Q register-resident queries (stride BLOCK for coalescing).
    const int q0 = blockIdx.x * QPB + threadIdx.x;
    f32x2 qx2[Q], qy2[Q], qz2[Q];
    float best[Q];
    #pragma unroll
    for (int k = 0; k < Q; ++k) {
        int qi = q0 + k * BLOCK;
        float x = q[3 * qi], y = q[3 * qi + 1], zz = q[3 * qi + 2];
        qx2[k] = (f32x2){x, x};
        qy2[k] = (f32x2){y, y};
        qz2[k] = (f32x2){zz, zz};
        best[k] = -3.4e38f;
    }
    __syncthreads();

    // Software-pipelined: prefetch pair j+1 while computing pair j.
    float4 A  = sA[0];
    float4 Bv = sB[0];
    #pragma unroll 2
    for (int j = 0; j < PAIRS; ++j) {
        const int jn = (j + 1) & (PAIRS - 1);    // branchless wrap
        float4 An  = sA[jn];
        float4 Bn  = sB[jn];
        f32x2 px = {A.x, A.y},   py = {A.z, A.w};
        f32x2 pz = {Bv.x, Bv.y}, pw = {Bv.z, Bv.w};
        #pragma unroll
        for (int k = 0; k < Q; ++k) {
            f32x2 t = pk_fma(qx2[k], px, pw);
            t = pk_fma(qy2[k], py, t);
            t = pk_fma(qz2[k], pz, t);
            best[k] = fmaxf(fmaxf(best[k], t.x), t.y);   // -> v_max3_f32
        }
        A = An; Bv = Bn;
    }

    // Max d' over chunks via order-preserving uint key (keys init to 0,
    // key_of is a monotone bijection, so atomicMax == float max).
    #pragma unroll
    for (int k = 0; k < Q; ++k)
        atomicMax(&keys[(size_t)z * NPTS + q0 + k * BLOCK], key_of(best[k]));
}

// 128 blocks: z = bid>>4 (dir*B+b), 16 segments of 512 queries each.
// dist(q) = |q|^2 - 2 * maxd'(q); accumulate mean into out[b].
__global__ __launch_bounds__(256) void chamfer_final(
    const float* __restrict__ tpl, const float* __restrict__ src,
    const unsigned* __restrict__ keys, float* __restrict__ out)
{
    __shared__ float red[256];
    const int z   = blockIdx.x >> 4;
    const int seg = blockIdx.x & 15;
    const float* qc = (z < B ? tpl : src) + (size_t)(z & (B - 1)) * NPTS * 3;

    float s = 0.f;
    const int lo = seg * (NPTS / 16);
    for (int i = lo + threadIdx.x; i < lo + NPTS / 16; i += 256) {
        float md = float_of(keys[(size_t)z * NPTS + i]);
        float x = qc[3 * i], y = qc[3 * i + 1], zz = qc[3 * i + 2];
        s += fmaf(md, -2.0f, x * x + y * y + zz * zz);
    }
    red[threadIdx.x] = s;
    __syncthreads();
    #pragma unroll
    for (int off = 128; off > 0; off >>= 1) {
        if (threadIdx.x < off) red[threadIdx.x] += red[threadIdx.x + off];
        __syncthreads();
    }
    if (threadIdx.x == 0)
        atomicAdd(&out[z & (B - 1)], red[0] * (1.0f / NPTS));
}

extern "C" void kernel_launch(void* const* d_in, const int* in_sizes, int n_in,
                              void* d_out, int out_size, void* d_ws, size_t ws_size,
                              hipStream_t stream) {
    const float* tpl = (const float*)d_in[0];
    const float* src = (const float*)d_in[1];
    float* out = (float*)d_out;
    unsigned* keys = (unsigned*)d_ws;            // 2*B*NPTS uints = 256 KB

    hipMemsetAsync(d_ws, 0x00, (size_t)2 * B * NPTS * sizeof(unsigned), stream);
    hipMemsetAsync(d_out, 0x00, (size_t)B * sizeof(float), stream);
    chamfer_chunk<<<dim3(QBLKS, CHUNKS, 2 * B), BLOCK, 0, stream>>>(tpl, src, keys);
    chamfer_final<<<128, 256, 0, stream>>>(tpl, src, keys, out);
}

// Round 2
// 41.945 us; speedup vs baseline: 1.3684x; 1.3375x over previous
//
#include <hip/hip_runtime.h>

// Chamfer distance, B=4, N=M=8192, fp32 [B][N][3], out[B] = d01+d10.
//
// R2: move the inner product to the matrix pipe. fp32-VALU floor is ~20.5us
// (3 FMA/pair at 78.6 G-FMA/cyc); measured 45-48us, VALUBusy ~60%, MfmaUtil 0.
// Rewrite: 2-way bf16 split q=qh+ql, p=ph+pl makes
//   d'(q,p) = q.p - 0.5|p|^2
// an exact-to-2^-18 dot product of length 14 <= K=16:
//   k0-2:  qh . ph      k3-5:  qh . pl      k6-8:  ql . ph
//   k9-10: 1 * (nh,nl)  (n = -0.5|p|^2, fp32-split)
//   k11-13: ql . pl     k14-15: 0
// One v_mfma_f32_32x32x16_bf16 covers 32q x 32p; VALU cost is just 32
// v_max_f32 per 2048 pairs (~0.032 cyc/pair vs 0.109 in the fp32 kernel).
// Point fragments are prepped ONCE (kernel 1) into ws; the sweep stages them
// to LDS with pure 16B coalesced copies and max-merges D tiles in registers.
// Per-query max d' combines across point-chunks via atomicMax on
// order-preserving uint keys; final pass reconstructs dist = |q|^2 - 2*maxd'
// in exact fp32 and reduces.

typedef __bf16 bf16x8 __attribute__((ext_vector_type(8)));
typedef float  f32x16 __attribute__((ext_vector_type(16)));

constexpr int B     = 4;
constexpr int NPTS  = 8192;
constexpr int BLOCK = 256;
constexpr int QPW   = 64;              // queries per wave (2 x 32-row A frags)
constexpr int QPB   = 256;             // 4 waves * 64
constexpr int QBLKS = NPTS / QPB;      // 32 query blocks per (b,dir)
constexpr int CH    = 4;               // point chunks per (b,dir)
constexpr int CPTS  = NPTS / CH;       // 2048 points per chunk
constexpr int SPTS  = 512;             // points per LDS pass (16 KB)
constexpr int NPASS = CPTS / SPTS;     // 4
constexpr int TPP   = SPTS / 32;       // 16 tiles per pass
constexpr size_t KEYBYTES = (size_t)2 * B * NPTS * sizeof(unsigned); // 256 KB

__device__ inline unsigned key_of(float f) {
    unsigned b = __float_as_uint(f);
    return b ^ (unsigned)(((int)b >> 31) | (int)0x80000000u);
}
__device__ inline float float_of(unsigned k) {
    unsigned b = (k & 0x80000000u) ? (k ^ 0x80000000u) : ~k;
    return __uint_as_float(b);
}

// ---- Kernel 1: prep point fragments (E0,E1 per point, 32 B) ---------------
// B-frag k-slots: g0(k0-7) = [pxh,pyh,pzh, pxl,pyl,pzl, pxh,pyh]
//                 g1(k8-15)= [pzh, nh, nl, pxl,pyl,pzl, 0, 0]
__global__ __launch_bounds__(BLOCK) void chamfer_prep(
    const float* __restrict__ tpl, const float* __restrict__ src,
    bf16x8* __restrict__ efrag)              // [8][NPTS][2]
{
    const int pt  = blockIdx.x * BLOCK + threadIdx.x;
    const int c   = blockIdx.y;              // dir*B + b
    const int b   = c & (B - 1);
    const int dir = c >> 2;
    const float* db = (dir == 0 ? src : tpl) + (size_t)b * NPTS * 3;

    float x = db[3 * pt], y = db[3 * pt + 1], z = db[3 * pt + 2];
    float n = -0.5f * (x * x + y * y + z * z);
    __bf16 hx = (__bf16)x, hy = (__bf16)y, hz = (__bf16)z;
    __bf16 lx = (__bf16)(x - (float)hx);
    __bf16 ly = (__bf16)(y - (float)hy);
    __bf16 lz = (__bf16)(z - (float)hz);
    __bf16 nh = (__bf16)n;
    __bf16 nl = (__bf16)(n - (float)nh);
    const __bf16 zb = (__bf16)0.0f;

    bf16x8 e0 = {hx, hy, hz, lx, ly, lz, hx, hy};
    bf16x8 e1 = {hz, nh, nl, lx, ly, lz, zb, zb};
    size_t base = ((size_t)c * NPTS + pt) * 2;
    efrag[base]     = e0;
    efrag[base + 1] = e1;
}

// ---- Kernel 2: MFMA sweep -------------------------------------------------
__global__ __launch_bounds__(BLOCK, 4) void chamfer_sweep(
    const float* __restrict__ tpl, const float* __restrict__ src,
    const bf16x8* __restrict__ efrag,
    unsigned* __restrict__ keys)             // [2*B][NPTS], key of max d'
{
    __shared__ bf16x8 sbuf[SPTS * 2];        // 16 KB: (pt,g) pairs, linear

    const int tid = threadIdx.x;
    const int l   = tid & 63;
    const int w   = tid >> 6;
    const int h   = l >> 5;                  // k-group (0: k0-7, 1: k8-15)
    const int r32 = l & 31;                  // A row / B col within tile
    const int c   = blockIdx.z;              // dir*B + b
    const int b   = c & (B - 1);
    const int dir = c >> 2;
    const float* q = (dir == 0 ? tpl : src) + (size_t)b * NPTS * 3;
    const int qbase  = blockIdx.x * QPB + w * QPW;
    const int cstart = blockIdx.y * CPTS;

    // A fragments: row = l&31, k = h*8 + e. Queries fixed per wave.
    // g0 = [qxh,qyh,qzh, qxh,qyh,qzh, qxl,qyl]; g1 = [qzl,1,1, qxl,qyl,qzl,0,0]
    const __bf16 one = (__bf16)1.0f, zb = (__bf16)0.0f;
    bf16x8 fa[2];
    #pragma unroll
    for (int f = 0; f < 2; ++f) {
        int qi = qbase + f * 32 + r32;
        float x = q[3 * qi], y = q[3 * qi + 1], z = q[3 * qi + 2];
        __bf16 hx = (__bf16)x, hy = (__bf16)y, hz = (__bf16)z;
        __bf16 lx = (__bf16)(x - (float)hx);
        __bf16 ly = (__bf16)(y - (float)hy);
        __bf16 lz = (__bf16)(z - (float)hz);
        if (h == 0) fa[f] = (bf16x8){hx, hy, hz, hx, hy, hz, lx, ly};
        else        fa[f] = (bf16x8){lz, one, one, lx, ly, lz, zb, zb};
    }

    f32x16 best0, best1, zc;
    #pragma unroll
    for (int r = 0; r < 16; ++r) { best0[r] = -3.4e38f; best1[r] = -3.4e38f; zc[r] = 0.0f; }

    // Stage pass 0 into registers.
    const bf16x8* eb = efrag + ((size_t)c * NPTS + cstart) * 2;
    bf16x8 rg[4];
    #pragma unroll
    for (int i = 0; i < 4; ++i) rg[i] = eb[tid + i * 256];

    for (int p = 0; p < NPASS; ++p) {
        __syncthreads();                     // prev sweep done reading sbuf
        #pragma unroll
        for (int i = 0; i < 4; ++i) sbuf[tid + i * 256] = rg[i];
        if (p + 1 < NPASS) {                 // issue next-pass loads early
            const bf16x8* ebn = eb + (size_t)(p + 1) * SPTS * 2;
            #pragma unroll
            for (int i = 0; i < 4; ++i) rg[i] = ebn[tid + i * 256];
        }
        __syncthreads();                     // sbuf ready

        #pragma unroll 2
        for (int t = 0; t < TPP; ++t) {
            bf16x8 bv = sbuf[t * 64 + r32 * 2 + h];   // contiguous 1024B/wave
            f32x16 d0 = __builtin_amdgcn_mfma_f32_32x32x16_bf16(fa[0], bv, zc, 0, 0, 0);
            f32x16 d1 = __builtin_amdgcn_mfma_f32_32x32x16_bf16(fa[1], bv, zc, 0, 0, 0);
            #pragma unroll
            for (int r = 0; r < 16; ++r) {
                best0[r] = fmaxf(best0[r], d0[r]);
                best1[r] = fmaxf(best1[r], d1[r]);
            }
        }
    }

    // Reduce over the 32 column-classes (lanes sharing h).
    #pragma unroll
    for (int m = 1; m < 32; m <<= 1) {
        #pragma unroll
        for (int r = 0; r < 16; ++r) {
            best0[r] = fmaxf(best0[r], __shfl_xor(best0[r], m, 64));
            best1[r] = fmaxf(best1[r], __shfl_xor(best1[r], m, 64));
        }
    }
    // D layout: col = lane&31, row = (r&3) + 8*(r>>2) + 4*h.
    if (r32 == 0) {
        unsigned* kz = keys + (size_t)c * NPTS;
        #pragma unroll
        for (int r = 0; r < 16; ++r) {
            int row = (r & 3) + 8 * (r >> 2) + 4 * h;
            atomicMax(&kz[qbase + row],      key_of(best0[r]));
            atomicMax(&kz[qbase + 32 + row], key_of(best1[r]));
        }
    }
}

// ---- Kernel 3: reconstruct dist = |q|^2 - 2*maxd', reduce to out[b] -------
__global__ __launch_bounds__(256) void chamfer_final(
    const float* __restrict__ tpl, const float* __restrict__ src,
    const unsigned* __restrict__ keys, float* __restrict__ out)
{
    __shared__ float red[256];
    const int z   = blockIdx.x >> 4;
    const int seg = blockIdx.x & 15;
    const float* qc = (z < B ? tpl : src) + (size_t)(z & (B - 1)) * NPTS * 3;

    float s = 0.f;
    const int lo = seg * (NPTS / 16);
    for (int i = lo + threadIdx.x; i < lo + NPTS / 16; i += 256) {
        float md = float_of(keys[(size_t)z * NPTS + i]);
        float x = qc[3 * i], y = qc[3 * i + 1], zz = qc[3 * i + 2];
        s += fmaf(md, -2.0f, x * x + y * y + zz * zz);
    }
    red[threadIdx.x] = s;
    __syncthreads();
    #pragma unroll
    for (int off = 128; off > 0; off >>= 1) {
        if (threadIdx.x < off) red[threadIdx.x] += red[threadIdx.x + off];
        __syncthreads();
    }
    if (threadIdx.x == 0)
        atomicAdd(&out[z & (B - 1)], red[0] * (1.0f / NPTS));
}

extern "C" void kernel_launch(void* const* d_in, const int* in_sizes, int n_in,
                              void* d_out, int out_size, void* d_ws, size_t ws_size,
                              hipStream_t stream) {
    const float* tpl = (const float*)d_in[0];
    const float* src = (const float*)d_in[1];
    float* out = (float*)d_out;
    unsigned* keys = (unsigned*)d_ws;                          // 256 KB
    bf16x8* efrag  = (bf16x8*)((char*)d_ws + KEYBYTES);        // 2 MB

    hipMemsetAsync(d_ws, 0x00, KEYBYTES, stream);              // key 0 = -max
    hipMemsetAsync(d_out, 0x00, (size_t)B * sizeof(float), stream);
    chamfer_prep <<<dim3(NPTS / BLOCK, 2 * B), BLOCK, 0, stream>>>(tpl, src, efrag);
    chamfer_sweep<<<dim3(QBLKS, CH, 2 * B),    BLOCK, 0, stream>>>(tpl, src, efrag, keys);
    chamfer_final<<<B * 16 * 2, 256, 0, stream>>>(tpl, src, keys, out);
}